// Round 6
// baseline (372.842 us; speedup 1.0000x reference)
//
#include <hip/hip_runtime.h>
#include <stdint.h>

#define BB   512
#define NN   512
#define MROWS (BB*NN)      // 262144
#define RT   (MROWS/64)    // 4096 row tiles of 64
#define EPSV 1e-5f

typedef unsigned short u16;
typedef __attribute__((ext_vector_type(8))) short bf16x8;
typedef __attribute__((ext_vector_type(4))) float f32x4;

// ---------- helpers ----------
__device__ __forceinline__ float read_mask(const void* mp, int r, int mode) {
  if (mode == 0) return ((const unsigned char*)mp)[r] ? 1.f : 0.f;
  if (mode == 1) return ((const unsigned int*)mp)[r] ? 1.f : 0.f;
  return ((const unsigned long long*)mp)[r] ? 1.f : 0.f;
}

__device__ __forceinline__ u16 f2bf(float f) {
  union { float f; unsigned int u; } v; v.f = f;
  unsigned int u = v.u;
  return (u16)((u + 0x7FFFu + ((u >> 16) & 1u)) >> 16);
}

__device__ __forceinline__ float bf2f(u16 b) {
  union { unsigned int u; float f; } t;
  t.u = ((unsigned int)b) << 16;
  return t.f;
}

// ---------- kernel 0: weight prep (blocks 0..511) + mask-layout detect (block 512) ----------
__global__ __launch_bounds__(256) void k_prep(
    const float* __restrict__ W2, const float* __restrict__ W3, const float* __restrict__ W4,
    u16* __restrict__ w2t, u16* __restrict__ w3t, u16* __restrict__ w4t,
    const unsigned char* __restrict__ mu, int* __restrict__ mode) {
  if (blockIdx.x == 512) {
    __shared__ int c1, c4;
    if (threadIdx.x == 0) { c1 = 0; c4 = 0; }
    __syncthreads();
    for (int i = threadIdx.x; i < 4096; i += 256) {
      const unsigned char b = mu[i];
      if (b) {
        if ((i & 3) == 1) atomicAdd(&c1, 1);
        if ((i & 7) == 4) atomicAdd(&c4, 1);
      }
    }
    __syncthreads();
    if (threadIdx.x == 0) *mode = c1 ? 0 : (c4 ? 1 : 2);
    return;
  }
  const int idx = blockIdx.x*256 + threadIdx.x;  // < 131072
  if (idx < 32768) {                 // W2t [256 n][128 k]
    const int n = idx >> 7, k = idx & 127;
    w2t[idx] = f2bf(W2[(size_t)k*256 + n]);
  } else if (idx < 98304) {          // W3t [256 n][256 k] (rows 0..256 of W3)
    const int j = idx - 32768;
    const int n = j >> 8, k = j & 255;
    w3t[j] = f2bf(W3[(size_t)k*256 + n]);
  } else {                           // W4t [128 n][256 k]
    const int j = idx - 98304;
    const int n = j >> 8, k = j & 255;
    w4t[j] = f2bf(W4[(size_t)k*128 + n]);
  }
}

// ---------- kernel 1: BN1 partial stats (grid 2048, 128 rows/blk) ----------
__global__ __launch_bounds__(256) void k_stats1(
    const float* __restrict__ x, const void* __restrict__ mask,
    const float* __restrict__ W1, const float* __restrict__ b1,
    const int* __restrict__ modep,
    float* __restrict__ s1sum, float* __restrict__ s1sq, int* __restrict__ cntpart) {
  const int mode = *modep;
  const int tid  = threadIdx.x;
  const int c    = tid & 127;
  const int half = tid >> 7;
  const int blk  = blockIdx.x;
  float w[6];
#pragma unroll
  for (int k = 0; k < 6; ++k) w[k] = W1[k*128 + c];
  const float bb = b1[c];
  float accS = 0.f, accQ = 0.f; int cnt = 0;
  for (int i = half; i < 128; i += 2) {
    const int r = blk*128 + i;
    const float mv = read_mask(mask, r, mode);
    const float* xr = x + (size_t)r*6;
    float h = bb;
#pragma unroll
    for (int k = 0; k < 6; ++k) h = fmaf(xr[k], w[k], h);
    accS += mv*h; accQ += mv*h*h;
    if (c == 0) cnt += (mv != 0.f);
  }
  __shared__ float rs[256], rq[256];
  __shared__ int rc[2];
  rs[tid] = accS; rq[tid] = accQ;
  if (c == 0) rc[half] = cnt;
  __syncthreads();
  if (tid < 128) {
    s1sum[(size_t)blk*128 + tid] = rs[tid] + rs[tid+128];
    s1sq [(size_t)blk*128 + tid] = rq[tid] + rq[tid+128];
    if (tid == 0) cntpart[blk] = rc[0] + rc[1];
  }
}

// ---------- kernel 1b: slab-reduce s1 partials 2048 -> 16 ----------
__global__ __launch_bounds__(256) void k_red1(
    const float* __restrict__ s1sum, const float* __restrict__ s1sq,
    float* __restrict__ mid1s, float* __restrict__ mid1q) {
  const int blk = blockIdx.x;  // 0..15
  const int c = threadIdx.x & 127, g = threadIdx.x >> 7;
  float s = 0.f, q = 0.f;
  for (int r = blk*128 + g*64; r < blk*128 + g*64 + 64; ++r) {
    s += s1sum[(size_t)r*128 + c];
    q += s1sq [(size_t)r*128 + c];
  }
  __shared__ float rs[256], rq[256];
  rs[threadIdx.x] = s; rq[threadIdx.x] = q;
  __syncthreads();
  if (threadIdx.x < 128) {
    mid1s[blk*128 + c] = rs[c] + rs[c+128];
    mid1q[blk*128 + c] = rq[c] + rq[c+128];
  }
}

// ---------- kernel 2: finalize BN1 -> folded W1p = W1*a1, c1p = b1*a1 + sh1 ----------
__global__ __launch_bounds__(128) void k_fin1(
    const float* __restrict__ mid1s, const float* __restrict__ mid1q,
    const int* __restrict__ cntpart,
    const float* __restrict__ W1, const float* __restrict__ b1,
    const float* __restrict__ g1, const float* __restrict__ be1,
    float* __restrict__ w1p, float* __restrict__ c1p, float* __restrict__ cntf) {
  const int c = threadIdx.x;
  float s = 0.f, q = 0.f;
#pragma unroll
  for (int b = 0; b < 16; ++b) { s += mid1s[b*128 + c]; q += mid1q[b*128 + c]; }
  __shared__ int cl[128];
  int cn = 0;
  for (int b = c*16; b < c*16 + 16; ++b) cn += cntpart[b];
  cl[c] = cn;
  __syncthreads();
  __shared__ float cshare;
  if (c == 0) {
    int t = 0;
    for (int i = 0; i < 128; ++i) t += cl[i];
    float cf = (float)t; if (cf < 1.f) cf = 1.f;
    cshare = cf; *cntf = cf;
  }
  __syncthreads();
  const float cf = cshare;
  const float mean = s / cf;
  float var = q / cf - mean*mean; if (var < 0.f) var = 0.f;
  const float a = g1[c] * rsqrtf(var + EPSV);
  const float sh = be1[c] - mean*a;
  c1p[c] = fmaf(b1[c], a, sh);
#pragma unroll
  for (int k = 0; k < 6; ++k) w1p[k*128 + c] = W1[k*128 + c] * a;
}

// ---------- MEGA kernel: GEMM1+BN1+ReLU+GEMM2+mask -> pool partials,
//            then GEMM3a (h@W3[0:256]) -> acc3 bf16 + BN2 stat partials ----------
// Single LDS tile: h1 aliases outt cols 0..127 (phase-2 acc lives in regs).
// LDS: 33792 + 1536 + 256 = 35584 B -> 4 blocks/CU
__global__ __launch_bounds__(256, 4) void k_mega(
    const float* __restrict__ x, const void* __restrict__ mask, const int* __restrict__ modep,
    const float* __restrict__ w1p, const float* __restrict__ c1p,
    const u16* __restrict__ W2t, const float* __restrict__ b2,
    const u16* __restrict__ W3t,
    u16* __restrict__ acc3buf, float* __restrict__ poolpart,
    float* __restrict__ s2sum, float* __restrict__ s2sq) {
  __shared__ u16 outt[64*264];   // 33792 B  [row][*] pitch 264: h1(k<128) -> h -> acc3
  __shared__ float xs[384];
  __shared__ float mk[64];
  const int mode = *modep;
  const int tid = threadIdx.x;
  const int rt = blockIdx.x;
  const int row0 = rt*64;
  const int b = rt >> 3, seg = rt & 7;
  // stage x rows + mask
  for (int i = tid; i < 384; i += 256) xs[i] = x[(size_t)row0*6 + i];
  if (tid < 64) mk[tid] = read_mask(mask, row0 + tid, mode);
  __syncthreads();
  // phase 1: h1n = relu(x@W1' + c1') bf16 into outt[row][0:128]
  {
    const int c0 = (tid & 31) * 4;
    const int r0 = (tid >> 5) * 8;
    float4 wv[6];
#pragma unroll
    for (int k = 0; k < 6; ++k) wv[k] = *(const float4*)(w1p + k*128 + c0);
    const float4 cc = *(const float4*)(c1p + c0);
#pragma unroll
    for (int r = 0; r < 8; ++r) {
      const int row = r0 + r;
      float xv[6];
#pragma unroll
      for (int k = 0; k < 6; ++k) xv[k] = xs[row*6 + k];
      float v0 = cc.x, v1 = cc.y, v2 = cc.z, v3 = cc.w;
#pragma unroll
      for (int k = 0; k < 6; ++k) {
        v0 = fmaf(xv[k], wv[k].x, v0);
        v1 = fmaf(xv[k], wv[k].y, v1);
        v2 = fmaf(xv[k], wv[k].z, v2);
        v3 = fmaf(xv[k], wv[k].w, v3);
      }
      ushort4 z;
      z.x = f2bf(v0 > 0.f ? v0 : 0.f);
      z.y = f2bf(v1 > 0.f ? v1 : 0.f);
      z.z = f2bf(v2 > 0.f ? v2 : 0.f);
      z.w = f2bf(v3 > 0.f ? v3 : 0.f);
      *(ushort4*)(outt + row*264 + c0) = z;
    }
  }
  __syncthreads();
  const int wave = tid >> 6, lane = tid & 63;
  const int lr = lane & 15, lq = lane >> 4;
  // phase 2: GEMM2 (64 x 256, K=128); wave w: cols [64w, 64w+64)
  {
    f32x4 acc[4][4];
#pragma unroll
    for (int r = 0; r < 4; ++r)
#pragma unroll
      for (int c = 0; c < 4; ++c) acc[r][c] = (f32x4){0.f,0.f,0.f,0.f};
#pragma unroll
    for (int kc = 0; kc < 128; kc += 32) {
      bf16x8 afr[4];
#pragma unroll
      for (int r = 0; r < 4; ++r)
        afr[r] = *(const bf16x8*)(outt + (r*16 + lr)*264 + kc + lq*8);
#pragma unroll
      for (int c = 0; c < 4; ++c) {
        const bf16x8 bfr = *(const bf16x8*)(W2t + (size_t)(wave*64 + c*16 + lr)*128 + kc + lq*8);
#pragma unroll
        for (int r = 0; r < 4; ++r)
          acc[r][c] = __builtin_amdgcn_mfma_f32_16x16x32_bf16(afr[r], bfr, acc[r][c], 0, 0, 0);
      }
    }
    __syncthreads();   // all reads of h1 done before epilogue overwrites outt
    // epilogue: h = (acc+b2)*mask -> outt (bf16) + pool col-max via shfl
#pragma unroll
    for (int c = 0; c < 4; ++c) {
      const int col = wave*64 + c*16 + lr;
      const float bb = b2[col];
      float cm = -1e38f;
#pragma unroll
      for (int r = 0; r < 4; ++r) {
#pragma unroll
        for (int i = 0; i < 4; ++i) {
          const int row = r*16 + lq*4 + i;
          const float v = (acc[r][c][i] + bb) * mk[row];
          outt[row*264 + col] = f2bf(v);
          cm = fmaxf(cm, v);
        }
      }
      cm = fmaxf(cm, __shfl_xor(cm, 16, 64));
      cm = fmaxf(cm, __shfl_xor(cm, 32, 64));
      if (lq == 0) poolpart[((size_t)(b*8 + seg))*256 + col] = cm;
    }
  }
  __syncthreads();
  // phase 3: GEMM3a (64 x 256, K=256) from outt; acc3 = h@W3a
  f32x4 acc3[4][4];
#pragma unroll
  for (int r = 0; r < 4; ++r)
#pragma unroll
    for (int c = 0; c < 4; ++c) acc3[r][c] = (f32x4){0.f,0.f,0.f,0.f};
#pragma unroll 2
  for (int kc = 0; kc < 256; kc += 32) {
    bf16x8 afr[4];
#pragma unroll
    for (int r = 0; r < 4; ++r)
      afr[r] = *(const bf16x8*)(outt + (r*16 + lr)*264 + kc + lq*8);
#pragma unroll
    for (int c = 0; c < 4; ++c) {
      const bf16x8 bfr = *(const bf16x8*)(W3t + (size_t)(wave*64 + c*16 + lr)*256 + kc + lq*8);
#pragma unroll
      for (int r = 0; r < 4; ++r)
        acc3[r][c] = __builtin_amdgcn_mfma_f32_16x16x32_bf16(afr[r], bfr, acc3[r][c], 0, 0, 0);
    }
  }
  __syncthreads();   // all waves done reading outt
  // epilogue: round acc3->bf16, stats partials on rounded values, write outt
#pragma unroll
  for (int c = 0; c < 4; ++c) {
    const int col = wave*64 + c*16 + lr;
    float sS = 0.f, sQ = 0.f;
#pragma unroll
    for (int r = 0; r < 4; ++r) {
#pragma unroll
      for (int i = 0; i < 4; ++i) {
        const int row = r*16 + lq*4 + i;
        const u16 w16 = f2bf(acc3[r][c][i]);
        const float w = bf2f(w16);
        outt[row*264 + col] = w16;
        sS += mk[row]*w;
        sQ += mk[row]*w*w;
      }
    }
    sS += __shfl_xor(sS, 16, 64);
    sS += __shfl_xor(sS, 32, 64);
    sQ += __shfl_xor(sQ, 16, 64);
    sQ += __shfl_xor(sQ, 32, 64);
    if (lq == 0) {
      s2sum[(size_t)rt*256 + col] = sS;
      s2sq [(size_t)rt*256 + col] = sQ;
    }
  }
  __syncthreads();
  // coalesced store acc3 tile -> global
  for (int it = tid; it < 64*32; it += 256) {
    const int row = it >> 5, c8 = it & 31;
    *(uint4*)(acc3buf + (size_t)(row0 + row)*256 + c8*8) = *(const uint4*)(outt + row*264 + c8*8);
  }
}

// ---------- pool reduce + P[b,:] = pooled[b]@W3[256:512] + b3 ----------
__global__ __launch_bounds__(256) void k_poolP(
    const float* __restrict__ poolpart, const float* __restrict__ W3,
    const float* __restrict__ b3, float* __restrict__ P) {
  __shared__ float pl[256];
  const int b = blockIdx.x, tid = threadIdx.x;
  float m = poolpart[((size_t)b*8)*256 + tid];
#pragma unroll
  for (int s = 1; s < 8; ++s) m = fmaxf(m, poolpart[((size_t)(b*8+s))*256 + tid]);
  pl[tid] = m;
  __syncthreads();
  float acc = b3[tid];
  for (int c = 0; c < 256; ++c) acc = fmaf(pl[c], W3[(size_t)(256 + c)*256 + tid], acc);
  P[(size_t)b*256 + tid] = acc;
}

// ---------- fold P into BN2 partials + reduce 512 batches -> 64 slabs ----------
__global__ __launch_bounds__(256) void k_red2(
    const float* __restrict__ s2sum, const float* __restrict__ s2sq,
    const int* __restrict__ cntpart, const float* __restrict__ P,
    float* __restrict__ midS, float* __restrict__ midQ) {
  const int slab = blockIdx.x;  // 0..63
  const int c = threadIdx.x;
  float accS = 0.f, accQ = 0.f;
  for (int b = slab*8; b < slab*8 + 8; ++b) {
    const float cntb = (float)(cntpart[4*b] + cntpart[4*b+1] + cntpart[4*b+2] + cntpart[4*b+3]);
    float S = 0.f, Q = 0.f;
#pragma unroll
    for (int s = 0; s < 8; ++s) {
      S += s2sum[(size_t)(b*8 + s)*256 + c];
      Q += s2sq [(size_t)(b*8 + s)*256 + c];
    }
    const float p = P[(size_t)b*256 + c];
    accS += fmaf(cntb, p, S);
    accQ += fmaf(cntb, p*p, fmaf(2.f*p, S, Q));
  }
  midS[slab*256 + c] = accS;
  midQ[slab*256 + c] = accQ;
}

// ---------- finalize BN2 ----------
__global__ __launch_bounds__(256) void k_fin2(
    const float* __restrict__ midS, const float* __restrict__ midQ,
    const float* __restrict__ cntf,
    const float* __restrict__ g2, const float* __restrict__ be2,
    float* __restrict__ a2, float* __restrict__ sh2) {
  const int c = threadIdx.x;
  float s = 0.f, q = 0.f;
#pragma unroll
  for (int k = 0; k < 64; ++k) { s += midS[k*256 + c]; q += midQ[k*256 + c]; }
  const float cf = *cntf;
  const float mean = s / cf;
  float var = q / cf - mean*mean; if (var < 0.f) var = 0.f;
  const float a = g2[c] * rsqrtf(var + EPSV);
  a2[c]  = a;
  sh2[c] = be2[c] - mean*a;
}

// ---------- GEMM4 (no LDS staging): A from global, BN2+ReLU in regs ----------
__global__ __launch_bounds__(256) void k_gemm4(
    const u16* __restrict__ acc3buf, const void* __restrict__ mask, const int* __restrict__ modep,
    const float* __restrict__ P, const float* __restrict__ a2, const float* __restrict__ sh2,
    const u16* __restrict__ W4t, const float* __restrict__ b4,
    float* __restrict__ outpart) {
  __shared__ float scl[256], sft[256];
  __shared__ float mk[64];
  const int mode = *modep;
  const int tid = threadIdx.x;
  const int rt = blockIdx.x;
  const int row0 = rt*64;
  const int b = rt >> 3, seg = rt & 7;
  if (tid < 64) mk[tid] = read_mask(mask, row0 + tid, mode);
  {  // fold P into shift: z = v*a2 + (P*a2 + sh2)
    const float aa = a2[tid];
    scl[tid] = aa;
    sft[tid] = fmaf(P[(size_t)b*256 + tid], aa, sh2[tid]);
  }
  __syncthreads();
  const int wave = tid >> 6, lane = tid & 63;
  const int lr = lane & 15, lq = lane >> 4;
  // GEMM4 (64 x 128, K=256); wave w: cols [32w, 32w+32)
  f32x4 acc2[4][2];
#pragma unroll
  for (int r = 0; r < 4; ++r)
#pragma unroll
    for (int c = 0; c < 2; ++c) acc2[r][c] = (f32x4){0.f,0.f,0.f,0.f};
#pragma unroll 2
  for (int kc = 0; kc < 256; kc += 32) {
    const int k0 = kc + lq*8;
    const float4 s0 = *(const float4*)(scl + k0);
    const float4 s1 = *(const float4*)(scl + k0 + 4);
    const float4 t0 = *(const float4*)(sft + k0);
    const float4 t1 = *(const float4*)(sft + k0 + 4);
    const float sc[8] = {s0.x, s0.y, s0.z, s0.w, s1.x, s1.y, s1.z, s1.w};
    const float sf[8] = {t0.x, t0.y, t0.z, t0.w, t1.x, t1.y, t1.z, t1.w};
    bf16x8 afr[4];
#pragma unroll
    for (int r = 0; r < 4; ++r) {
      const bf16x8 raw = *(const bf16x8*)(acc3buf + (size_t)(row0 + r*16 + lr)*256 + k0);
      const u16* rp = (const u16*)&raw;
      u16 z[8];
#pragma unroll
      for (int j = 0; j < 8; ++j) {
        const float v = fmaf(bf2f(rp[j]), sc[j], sf[j]);
        z[j] = f2bf(v > 0.f ? v : 0.f);
      }
      afr[r] = *(const bf16x8*)z;
    }
#pragma unroll
    for (int c = 0; c < 2; ++c) {
      const bf16x8 bfr = *(const bf16x8*)(W4t + (size_t)(wave*32 + c*16 + lr)*256 + k0);
#pragma unroll
      for (int r = 0; r < 4; ++r)
        acc2[r][c] = __builtin_amdgcn_mfma_f32_16x16x32_bf16(afr[r], bfr, acc2[r][c], 0, 0, 0);
    }
  }
#pragma unroll
  for (int c = 0; c < 2; ++c) {
    const int col = wave*32 + c*16 + lr;
    const float bb = b4[col];
    float cm = -1e38f;
#pragma unroll
    for (int r = 0; r < 4; ++r) {
#pragma unroll
      for (int i = 0; i < 4; ++i) {
        const int row = r*16 + lq*4 + i;
        cm = fmaxf(cm, (acc2[r][c][i] + bb) * mk[row]);
      }
    }
    cm = fmaxf(cm, __shfl_xor(cm, 16, 64));
    cm = fmaxf(cm, __shfl_xor(cm, 32, 64));
    if (lq == 0) outpart[((size_t)(b*8 + seg))*128 + col] = cm;
  }
}

// ---------- reduce 8 segment maxima -> out[b,e] ----------
__global__ __launch_bounds__(256) void k_outred(
    const float* __restrict__ outpart, float* __restrict__ out) {
  const int idx = blockIdx.x*256 + threadIdx.x;  // < 65536
  const int b = idx >> 7, e = idx & 127;
  float m = outpart[((size_t)b*8)*128 + e];
#pragma unroll
  for (int s = 1; s < 8; ++s) m = fmaxf(m, outpart[((size_t)(b*8 + s))*128 + e]);
  out[idx] = m;
}

extern "C" void kernel_launch(void* const* d_in, const int* in_sizes, int n_in,
                              void* d_out, int out_size, void* d_ws, size_t ws_size,
                              hipStream_t stream) {
  const float* x    = (const float*)d_in[0];
  const void*  mask = d_in[1];
  const float* W1   = (const float*)d_in[2];
  const float* b1   = (const float*)d_in[3];
  const float* g1   = (const float*)d_in[4];
  const float* be1  = (const float*)d_in[5];
  const float* W2   = (const float*)d_in[6];
  const float* b2   = (const float*)d_in[7];
  const float* W3   = (const float*)d_in[8];
  const float* b3   = (const float*)d_in[9];
  const float* g2   = (const float*)d_in[10];
  const float* be2  = (const float*)d_in[11];
  const float* W4   = (const float*)d_in[12];
  const float* b4   = (const float*)d_in[13];
  float* out = (float*)d_out;

  char* ws = (char*)d_ws;
  size_t off = 0;
  auto take = [&](size_t bytes) -> char* {
    char* p = ws + off;
    off = (off + bytes + 255) & ~(size_t)255;
    return p;
  };
  u16*   acc3buf = (u16*)  take((size_t)MROWS*256*2);   // 128 MiB
  float* s1sum   = (float*)take((size_t)2048*128*4);
  float* s1sq    = (float*)take((size_t)2048*128*4);
  int*   cntpart = (int*)  take((size_t)2048*4);
  float* mid1s   = (float*)take((size_t)16*128*4);
  float* mid1q   = (float*)take((size_t)16*128*4);
  float* w1p     = (float*)take(768*4);
  float* c1p     = (float*)take(128*4);
  float* cntf    = (float*)take(256);
  float* poolpart= (float*)take((size_t)512*8*256*4);
  float* P       = (float*)take((size_t)512*256*4);
  float* s2sum   = (float*)take((size_t)4096*256*4);
  float* s2sq    = (float*)take((size_t)4096*256*4);
  float* midS    = (float*)take((size_t)64*256*4);
  float* midQ    = (float*)take((size_t)64*256*4);
  float* a2      = (float*)take(256*4);
  float* sh2     = (float*)take(256*4);
  float* outpart = (float*)take((size_t)512*8*128*4);
  int*   modep   = (int*)  take(256);
  u16*   w2t     = (u16*)  take((size_t)256*128*2);
  u16*   w3t     = (u16*)  take((size_t)256*256*2);
  u16*   w4t     = (u16*)  take((size_t)128*256*2);

  k_prep<<<513, 256, 0, stream>>>(W2, W3, W4, w2t, w3t, w4t,
                                  (const unsigned char*)mask, modep);
  k_stats1<<<2048, 256, 0, stream>>>(x, mask, W1, b1, modep, s1sum, s1sq, cntpart);
  k_red1<<<16, 256, 0, stream>>>(s1sum, s1sq, mid1s, mid1q);
  k_fin1<<<1, 128, 0, stream>>>(mid1s, mid1q, cntpart, W1, b1, g1, be1, w1p, c1p, cntf);
  k_mega<<<RT, 256, 0, stream>>>(x, mask, modep, w1p, c1p, w2t, b2, w3t,
                                 acc3buf, poolpart, s2sum, s2sq);
  k_poolP<<<512, 256, 0, stream>>>(poolpart, W3, b3, P);
  k_red2<<<64, 256, 0, stream>>>(s2sum, s2sq, cntpart, P, midS, midQ);
  k_fin2<<<1, 256, 0, stream>>>(midS, midQ, cntf, g2, be2, a2, sh2);
  k_gemm4<<<RT, 256, 0, stream>>>(acc3buf, mask, modep, P, a2, sh2, w4t, b4, outpart);
  k_outred<<<256, 256, 0, stream>>>(outpart, out);
}

// Round 7
// 339.109 us; speedup vs baseline: 1.0995x; 1.0995x over previous
//
#include <hip/hip_runtime.h>
#include <stdint.h>

#define BB   512
#define NN   512
#define MROWS (BB*NN)      // 262144
#define RT   (MROWS/64)    // 4096 row tiles of 64
#define EPSV 1e-5f

typedef unsigned short u16;
typedef __attribute__((ext_vector_type(8))) short bf16x8;
typedef __attribute__((ext_vector_type(4))) float f32x4;

// ---------- helpers ----------
__device__ __forceinline__ float read_mask(const void* mp, int r, int mode) {
  if (mode == 0) return ((const unsigned char*)mp)[r] ? 1.f : 0.f;
  if (mode == 1) return ((const unsigned int*)mp)[r] ? 1.f : 0.f;
  return ((const unsigned long long*)mp)[r] ? 1.f : 0.f;
}

// round-to-nearest-even (weights, one-time)
__device__ __forceinline__ u16 f2bf(float f) {
  union { float f; unsigned int u; } v; v.f = f;
  unsigned int u = v.u;
  return (u16)((u + 0x7FFFu + ((u >> 16) & 1u)) >> 16);
}

// fast round-half-up (hot paths; <=1 ulp vs RNE)
__device__ __forceinline__ u16 f2bf_f(float f) {
  union { float f; unsigned int u; } v; v.f = f;
  return (u16)((v.u + 0x8000u) >> 16);
}

__device__ __forceinline__ float bf2f(u16 b) {
  union { unsigned int u; float f; } t;
  t.u = ((unsigned int)b) << 16;
  return t.f;
}

// ---------- kernel 0: weight prep (blocks 0..511) + mask-layout detect (block 512) ----------
__global__ __launch_bounds__(256) void k_prep(
    const float* __restrict__ W2, const float* __restrict__ W3, const float* __restrict__ W4,
    u16* __restrict__ w2t, u16* __restrict__ w3t, u16* __restrict__ w4t,
    const unsigned char* __restrict__ mu, int* __restrict__ mode) {
  if (blockIdx.x == 512) {
    __shared__ int c1, c4;
    if (threadIdx.x == 0) { c1 = 0; c4 = 0; }
    __syncthreads();
    for (int i = threadIdx.x; i < 4096; i += 256) {
      const unsigned char b = mu[i];
      if (b) {
        if ((i & 3) == 1) atomicAdd(&c1, 1);
        if ((i & 7) == 4) atomicAdd(&c4, 1);
      }
    }
    __syncthreads();
    if (threadIdx.x == 0) *mode = c1 ? 0 : (c4 ? 1 : 2);
    return;
  }
  const int idx = blockIdx.x*256 + threadIdx.x;  // < 131072
  if (idx < 32768) {                 // W2t [256 n][128 k]
    const int n = idx >> 7, k = idx & 127;
    w2t[idx] = f2bf(W2[(size_t)k*256 + n]);
  } else if (idx < 98304) {          // W3t [256 n][256 k] (rows 0..256 of W3)
    const int j = idx - 32768;
    const int n = j >> 8, k = j & 255;
    w3t[j] = f2bf(W3[(size_t)k*256 + n]);
  } else {                           // W4t [128 n][256 k]
    const int j = idx - 98304;
    const int n = j >> 8, k = j & 255;
    w4t[j] = f2bf(W4[(size_t)k*128 + n]);
  }
}

// ---------- kernel 1: BN1 partial stats (grid 2048, 128 rows/blk) ----------
__global__ __launch_bounds__(256) void k_stats1(
    const float* __restrict__ x, const void* __restrict__ mask,
    const float* __restrict__ W1, const float* __restrict__ b1,
    const int* __restrict__ modep,
    float* __restrict__ s1sum, float* __restrict__ s1sq, int* __restrict__ cntpart) {
  const int mode = *modep;
  const int tid  = threadIdx.x;
  const int c    = tid & 127;
  const int half = tid >> 7;
  const int blk  = blockIdx.x;
  float w[6];
#pragma unroll
  for (int k = 0; k < 6; ++k) w[k] = W1[k*128 + c];
  const float bb = b1[c];
  float accS = 0.f, accQ = 0.f; int cnt = 0;
  for (int i = half; i < 128; i += 2) {
    const int r = blk*128 + i;
    const float mv = read_mask(mask, r, mode);
    const float* xr = x + (size_t)r*6;
    float h = bb;
#pragma unroll
    for (int k = 0; k < 6; ++k) h = fmaf(xr[k], w[k], h);
    accS += mv*h; accQ += mv*h*h;
    if (c == 0) cnt += (mv != 0.f);
  }
  __shared__ float rs[256], rq[256];
  __shared__ int rc[2];
  rs[tid] = accS; rq[tid] = accQ;
  if (c == 0) rc[half] = cnt;
  __syncthreads();
  if (tid < 128) {
    s1sum[(size_t)blk*128 + tid] = rs[tid] + rs[tid+128];
    s1sq [(size_t)blk*128 + tid] = rq[tid] + rq[tid+128];
    if (tid == 0) cntpart[blk] = rc[0] + rc[1];
  }
}

// ---------- kernel 1b: slab-reduce s1 partials 2048 -> 16 ----------
__global__ __launch_bounds__(256) void k_red1(
    const float* __restrict__ s1sum, const float* __restrict__ s1sq,
    float* __restrict__ mid1s, float* __restrict__ mid1q) {
  const int blk = blockIdx.x;  // 0..15
  const int c = threadIdx.x & 127, g = threadIdx.x >> 7;
  float s = 0.f, q = 0.f;
  for (int r = blk*128 + g*64; r < blk*128 + g*64 + 64; ++r) {
    s += s1sum[(size_t)r*128 + c];
    q += s1sq [(size_t)r*128 + c];
  }
  __shared__ float rs[256], rq[256];
  rs[threadIdx.x] = s; rq[threadIdx.x] = q;
  __syncthreads();
  if (threadIdx.x < 128) {
    mid1s[blk*128 + c] = rs[c] + rs[c+128];
    mid1q[blk*128 + c] = rq[c] + rq[c+128];
  }
}

// ---------- kernel 2: finalize BN1 -> folded W1p = W1*a1, c1p = b1*a1 + sh1 ----------
__global__ __launch_bounds__(128) void k_fin1(
    const float* __restrict__ mid1s, const float* __restrict__ mid1q,
    const int* __restrict__ cntpart,
    const float* __restrict__ W1, const float* __restrict__ b1,
    const float* __restrict__ g1, const float* __restrict__ be1,
    float* __restrict__ w1p, float* __restrict__ c1p, float* __restrict__ cntf) {
  const int c = threadIdx.x;
  float s = 0.f, q = 0.f;
#pragma unroll
  for (int b = 0; b < 16; ++b) { s += mid1s[b*128 + c]; q += mid1q[b*128 + c]; }
  __shared__ int cl[128];
  int cn = 0;
  for (int b = c*16; b < c*16 + 16; ++b) cn += cntpart[b];
  cl[c] = cn;
  __syncthreads();
  __shared__ float cshare;
  if (c == 0) {
    int t = 0;
    for (int i = 0; i < 128; ++i) t += cl[i];
    float cf = (float)t; if (cf < 1.f) cf = 1.f;
    cshare = cf; *cntf = cf;
  }
  __syncthreads();
  const float cf = cshare;
  const float mean = s / cf;
  float var = q / cf - mean*mean; if (var < 0.f) var = 0.f;
  const float a = g1[c] * rsqrtf(var + EPSV);
  const float sh = be1[c] - mean*a;
  c1p[c] = fmaf(b1[c], a, sh);
#pragma unroll
  for (int k = 0; k < 6; ++k) w1p[k*128 + c] = W1[k*128 + c] * a;
}

// ---------- MEGA kernel: GEMM1+BN1+ReLU+GEMM2+mask -> pool partials,
//            then GEMM3a (h@W3[0:256]) -> acc3 bf16 + BN2 stat partials ----------
// LDS: 33792 + 1536 + 256 = 35584 B -> 4 blocks/CU
__global__ __launch_bounds__(256, 4) void k_mega(
    const float* __restrict__ x, const void* __restrict__ mask, const int* __restrict__ modep,
    const float* __restrict__ w1p, const float* __restrict__ c1p,
    const u16* __restrict__ W2t, const float* __restrict__ b2,
    const u16* __restrict__ W3t,
    u16* __restrict__ acc3buf, float* __restrict__ poolpart,
    float* __restrict__ s2sum, float* __restrict__ s2sq) {
  __shared__ u16 outt[64*264];   // 33792 B  [row][*] pitch 264: h1(k<128) -> h -> acc3
  __shared__ float xs[384];
  __shared__ float mk[64];
  const int mode = *modep;
  const int tid = threadIdx.x;
  const int rt = blockIdx.x;
  const int row0 = rt*64;
  const int b = rt >> 3, seg = rt & 7;
  for (int i = tid; i < 384; i += 256) xs[i] = x[(size_t)row0*6 + i];
  if (tid < 64) mk[tid] = read_mask(mask, row0 + tid, mode);
  __syncthreads();
  // phase 1: h1n = relu(x@W1' + c1') bf16 into outt[row][0:128]
  {
    const int c0 = (tid & 31) * 4;
    const int r0 = (tid >> 5) * 8;
    float4 wv[6];
#pragma unroll
    for (int k = 0; k < 6; ++k) wv[k] = *(const float4*)(w1p + k*128 + c0);
    const float4 cc = *(const float4*)(c1p + c0);
#pragma unroll
    for (int r = 0; r < 8; ++r) {
      const int row = r0 + r;
      float xv[6];
#pragma unroll
      for (int k = 0; k < 6; ++k) xv[k] = xs[row*6 + k];
      float v0 = cc.x, v1 = cc.y, v2 = cc.z, v3 = cc.w;
#pragma unroll
      for (int k = 0; k < 6; ++k) {
        v0 = fmaf(xv[k], wv[k].x, v0);
        v1 = fmaf(xv[k], wv[k].y, v1);
        v2 = fmaf(xv[k], wv[k].z, v2);
        v3 = fmaf(xv[k], wv[k].w, v3);
      }
      ushort4 z;
      z.x = f2bf_f(v0 > 0.f ? v0 : 0.f);
      z.y = f2bf_f(v1 > 0.f ? v1 : 0.f);
      z.z = f2bf_f(v2 > 0.f ? v2 : 0.f);
      z.w = f2bf_f(v3 > 0.f ? v3 : 0.f);
      *(ushort4*)(outt + row*264 + c0) = z;
    }
  }
  __syncthreads();
  const int wave = tid >> 6, lane = tid & 63;
  const int lr = lane & 15, lq = lane >> 4;
  // phase 2: GEMM2 (64 x 256, K=128); wave w: cols [64w, 64w+64)
  {
    f32x4 acc[4][4];
#pragma unroll
    for (int r = 0; r < 4; ++r)
#pragma unroll
      for (int c = 0; c < 4; ++c) acc[r][c] = (f32x4){0.f,0.f,0.f,0.f};
#pragma unroll
    for (int kc = 0; kc < 128; kc += 32) {
      bf16x8 afr[4];
#pragma unroll
      for (int r = 0; r < 4; ++r)
        afr[r] = *(const bf16x8*)(outt + (r*16 + lr)*264 + kc + lq*8);
#pragma unroll
      for (int c = 0; c < 4; ++c) {
        const bf16x8 bfr = *(const bf16x8*)(W2t + (size_t)(wave*64 + c*16 + lr)*128 + kc + lq*8);
#pragma unroll
        for (int r = 0; r < 4; ++r)
          acc[r][c] = __builtin_amdgcn_mfma_f32_16x16x32_bf16(afr[r], bfr, acc[r][c], 0, 0, 0);
      }
    }
    __syncthreads();   // all reads of h1 done before epilogue overwrites outt
#pragma unroll
    for (int c = 0; c < 4; ++c) {
      const int col = wave*64 + c*16 + lr;
      const float bb = b2[col];
      float cm = -1e38f;
#pragma unroll
      for (int r = 0; r < 4; ++r) {
#pragma unroll
        for (int i = 0; i < 4; ++i) {
          const int row = r*16 + lq*4 + i;
          const float v = (acc[r][c][i] + bb) * mk[row];
          outt[row*264 + col] = f2bf_f(v);
          cm = fmaxf(cm, v);
        }
      }
      cm = fmaxf(cm, __shfl_xor(cm, 16, 64));
      cm = fmaxf(cm, __shfl_xor(cm, 32, 64));
      if (lq == 0) poolpart[((size_t)(b*8 + seg))*256 + col] = cm;
    }
  }
  __syncthreads();
  // phase 3: GEMM3a (64 x 256, K=256) from outt; acc3 = h@W3a
  f32x4 acc3[4][4];
#pragma unroll
  for (int r = 0; r < 4; ++r)
#pragma unroll
    for (int c = 0; c < 4; ++c) acc3[r][c] = (f32x4){0.f,0.f,0.f,0.f};
#pragma unroll 2
  for (int kc = 0; kc < 256; kc += 32) {
    bf16x8 afr[4];
#pragma unroll
    for (int r = 0; r < 4; ++r)
      afr[r] = *(const bf16x8*)(outt + (r*16 + lr)*264 + kc + lq*8);
#pragma unroll
    for (int c = 0; c < 4; ++c) {
      const bf16x8 bfr = *(const bf16x8*)(W3t + (size_t)(wave*64 + c*16 + lr)*256 + kc + lq*8);
#pragma unroll
      for (int r = 0; r < 4; ++r)
        acc3[r][c] = __builtin_amdgcn_mfma_f32_16x16x32_bf16(afr[r], bfr, acc3[r][c], 0, 0, 0);
    }
  }
  __syncthreads();   // all waves done reading outt
  // epilogue: stats partials on f32 acc3, round->bf16 into outt
#pragma unroll
  for (int c = 0; c < 4; ++c) {
    const int col = wave*64 + c*16 + lr;
    float sS = 0.f, sQ = 0.f;
#pragma unroll
    for (int r = 0; r < 4; ++r) {
#pragma unroll
      for (int i = 0; i < 4; ++i) {
        const int row = r*16 + lq*4 + i;
        const float v = acc3[r][c][i];
        outt[row*264 + col] = f2bf_f(v);
        sS += mk[row]*v;
        sQ += mk[row]*v*v;
      }
    }
    sS += __shfl_xor(sS, 16, 64);
    sS += __shfl_xor(sS, 32, 64);
    sQ += __shfl_xor(sQ, 16, 64);
    sQ += __shfl_xor(sQ, 32, 64);
    if (lq == 0) {
      s2sum[(size_t)rt*256 + col] = sS;
      s2sq [(size_t)rt*256 + col] = sQ;
    }
  }
  __syncthreads();
  // coalesced store acc3 tile -> global
  for (int it = tid; it < 64*32; it += 256) {
    const int row = it >> 5, c8 = it & 31;
    *(uint4*)(acc3buf + (size_t)(row0 + row)*256 + c8*8) = *(const uint4*)(outt + row*264 + c8*8);
  }
}

// ---------- pool reduce + P + fold BN2 partials (8 batches/block, 64 blocks) ----------
__global__ __launch_bounds__(256) void k_poolred(
    const float* __restrict__ poolpart, const float* __restrict__ W3,
    const float* __restrict__ b3,
    const float* __restrict__ s2sum, const float* __restrict__ s2sq,
    const int* __restrict__ cntpart,
    float* __restrict__ P, float* __restrict__ midS, float* __restrict__ midQ) {
  __shared__ float pl[8][256];
  const int slab = blockIdx.x;  // 0..63, batches slab*8..slab*8+7
  const int c = threadIdx.x;
  const int b0 = slab*8;
#pragma unroll
  for (int bi = 0; bi < 8; ++bi) {
    const int b = b0 + bi;
    float m = poolpart[((size_t)b*8)*256 + c];
#pragma unroll
    for (int s = 1; s < 8; ++s) m = fmaxf(m, poolpart[((size_t)(b*8+s))*256 + c]);
    pl[bi][c] = m;
  }
  __syncthreads();
  // P[b][c] = b3[c] + sum_k pl[b][k] * W3[(256+k)*256 + c]  (W3 value shared across 8 batches)
  float acc[8];
  const float bb = b3[c];
#pragma unroll
  for (int bi = 0; bi < 8; ++bi) acc[bi] = bb;
  for (int k = 0; k < 256; ++k) {
    const float w = W3[(size_t)(256 + k)*256 + c];
#pragma unroll
    for (int bi = 0; bi < 8; ++bi) acc[bi] = fmaf(pl[bi][k], w, acc[bi]);
  }
  float accS = 0.f, accQ = 0.f;
#pragma unroll
  for (int bi = 0; bi < 8; ++bi) {
    const int b = b0 + bi;
    P[(size_t)b*256 + c] = acc[bi];
    const float cntb = (float)(cntpart[4*b] + cntpart[4*b+1] + cntpart[4*b+2] + cntpart[4*b+3]);
    float S = 0.f, Q = 0.f;
#pragma unroll
    for (int s = 0; s < 8; ++s) {
      S += s2sum[(size_t)(b*8 + s)*256 + c];
      Q += s2sq [(size_t)(b*8 + s)*256 + c];
    }
    const float p = acc[bi];
    accS += fmaf(cntb, p, S);
    accQ += fmaf(cntb, p*p, fmaf(2.f*p, S, Q));
  }
  midS[slab*256 + c] = accS;
  midQ[slab*256 + c] = accQ;
}

// ---------- finalize BN2 ----------
__global__ __launch_bounds__(256) void k_fin2(
    const float* __restrict__ midS, const float* __restrict__ midQ,
    const float* __restrict__ cntf,
    const float* __restrict__ g2, const float* __restrict__ be2,
    float* __restrict__ a2, float* __restrict__ sh2) {
  const int c = threadIdx.x;
  float s = 0.f, q = 0.f;
#pragma unroll
  for (int k = 0; k < 64; ++k) { s += midS[k*256 + c]; q += midQ[k*256 + c]; }
  const float cf = *cntf;
  const float mean = s / cf;
  float var = q / cf - mean*mean; if (var < 0.f) var = 0.f;
  const float a = g2[c] * rsqrtf(var + EPSV);
  a2[c]  = a;
  sh2[c] = be2[c] - mean*a;
}

// ---------- GEMM4 (LDS-staged): z = relu((acc3+P)*a2+sh2); col-max of z@W4+b4, masked ----
__global__ __launch_bounds__(256, 4) void k_gemm4(
    const u16* __restrict__ acc3buf, const void* __restrict__ mask, const int* __restrict__ modep,
    const float* __restrict__ P, const float* __restrict__ a2, const float* __restrict__ sh2,
    const u16* __restrict__ W4t, const float* __restrict__ b4,
    float* __restrict__ outpart) {
  __shared__ u16 a2t[64*264];   // 33792 B  [row][k] pitch 264
  __shared__ float a2l[256], s2b[256];
  __shared__ float mk[64];
  const int mode = *modep;
  const int tid = threadIdx.x;
  const int rt = blockIdx.x;
  const int row0 = rt*64;
  const int b = rt >> 3, seg = rt & 7;
  if (tid < 64) mk[tid] = read_mask(mask, row0 + tid, mode);
  {  // fold P into shift: z = v*a2 + (P*a2 + sh2)
    const float aa = a2[tid];
    a2l[tid] = aa;
    s2b[tid] = fmaf(P[(size_t)b*256 + tid], aa, sh2[tid]);
  }
  __syncthreads();
  // stage + BN2 + ReLU -> a2t (coalesced once-per-block tile load)
  for (int it = tid; it < 64*32; it += 256) {
    const int row = it >> 5, c8 = it & 31;
    const uint4 u = *(const uint4*)(acc3buf + (size_t)(row0 + row)*256 + c8*8);
    const u16* us = (const u16*)&u;
    u16 z8[8];
#pragma unroll
    for (int j = 0; j < 8; ++j) {
      const int cc = c8*8 + j;
      const float z = fmaf(bf2f(us[j]), a2l[cc], s2b[cc]);
      z8[j] = f2bf_f(z > 0.f ? z : 0.f);
    }
    *(uint4*)(a2t + row*264 + c8*8) = *(const uint4*)z8;
  }
  __syncthreads();
  const int wave = tid >> 6, lane = tid & 63;
  const int lr = lane & 15, lq = lane >> 4;
  // GEMM4 (64 x 128, K=256); wave w: cols [32w, 32w+32)
  f32x4 acc2[4][2];
#pragma unroll
  for (int r = 0; r < 4; ++r)
#pragma unroll
    for (int c = 0; c < 2; ++c) acc2[r][c] = (f32x4){0.f,0.f,0.f,0.f};
#pragma unroll 2
  for (int kc = 0; kc < 256; kc += 32) {
    bf16x8 afr[4];
#pragma unroll
    for (int r = 0; r < 4; ++r)
      afr[r] = *(const bf16x8*)(a2t + (r*16 + lr)*264 + kc + lq*8);
#pragma unroll
    for (int c = 0; c < 2; ++c) {
      const bf16x8 bfr = *(const bf16x8*)(W4t + (size_t)(wave*32 + c*16 + lr)*256 + kc + lq*8);
#pragma unroll
      for (int r = 0; r < 4; ++r)
        acc2[r][c] = __builtin_amdgcn_mfma_f32_16x16x32_bf16(afr[r], bfr, acc2[r][c], 0, 0, 0);
    }
  }
#pragma unroll
  for (int c = 0; c < 2; ++c) {
    const int col = wave*32 + c*16 + lr;
    const float bb = b4[col];
    float cm = -1e38f;
#pragma unroll
    for (int r = 0; r < 4; ++r) {
#pragma unroll
      for (int i = 0; i < 4; ++i) {
        const int row = r*16 + lq*4 + i;
        cm = fmaxf(cm, (acc2[r][c][i] + bb) * mk[row]);
      }
    }
    cm = fmaxf(cm, __shfl_xor(cm, 16, 64));
    cm = fmaxf(cm, __shfl_xor(cm, 32, 64));
    if (lq == 0) outpart[((size_t)(b*8 + seg))*128 + col] = cm;
  }
}

// ---------- reduce 8 segment maxima -> out[b,e] ----------
__global__ __launch_bounds__(256) void k_outred(
    const float* __restrict__ outpart, float* __restrict__ out) {
  const int idx = blockIdx.x*256 + threadIdx.x;  // < 65536
  const int b = idx >> 7, e = idx & 127;
  float m = outpart[((size_t)b*8)*128 + e];
#pragma unroll
  for (int s = 1; s < 8; ++s) m = fmaxf(m, outpart[((size_t)(b*8 + s))*128 + e]);
  out[idx] = m;
}

extern "C" void kernel_launch(void* const* d_in, const int* in_sizes, int n_in,
                              void* d_out, int out_size, void* d_ws, size_t ws_size,
                              hipStream_t stream) {
  const float* x    = (const float*)d_in[0];
  const void*  mask = d_in[1];
  const float* W1   = (const float*)d_in[2];
  const float* b1   = (const float*)d_in[3];
  const float* g1   = (const float*)d_in[4];
  const float* be1  = (const float*)d_in[5];
  const float* W2   = (const float*)d_in[6];
  const float* b2   = (const float*)d_in[7];
  const float* W3   = (const float*)d_in[8];
  const float* b3   = (const float*)d_in[9];
  const float* g2   = (const float*)d_in[10];
  const float* be2  = (const float*)d_in[11];
  const float* W4   = (const float*)d_in[12];
  const float* b4   = (const float*)d_in[13];
  float* out = (float*)d_out;

  char* ws = (char*)d_ws;
  size_t off = 0;
  auto take = [&](size_t bytes) -> char* {
    char* p = ws + off;
    off = (off + bytes + 255) & ~(size_t)255;
    return p;
  };
  u16*   acc3buf = (u16*)  take((size_t)MROWS*256*2);   // 128 MiB
  float* s1sum   = (float*)take((size_t)2048*128*4);
  float* s1sq    = (float*)take((size_t)2048*128*4);
  int*   cntpart = (int*)  take((size_t)2048*4);
  float* mid1s   = (float*)take((size_t)16*128*4);
  float* mid1q   = (float*)take((size_t)16*128*4);
  float* w1p     = (float*)take(768*4);
  float* c1p     = (float*)take(128*4);
  float* cntf    = (float*)take(256);
  float* poolpart= (float*)take((size_t)512*8*256*4);
  float* P       = (float*)take((size_t)512*256*4);
  float* s2sum   = (float*)take((size_t)4096*256*4);
  float* s2sq    = (float*)take((size_t)4096*256*4);
  float* midS    = (float*)take((size_t)64*256*4);
  float* midQ    = (float*)take((size_t)64*256*4);
  float* a2      = (float*)take(256*4);
  float* sh2     = (float*)take(256*4);
  float* outpart = (float*)take((size_t)512*8*128*4);
  int*   modep   = (int*)  take(256);
  u16*   w2t     = (u16*)  take((size_t)256*128*2);
  u16*   w3t     = (u16*)  take((size_t)256*256*2);
  u16*   w4t     = (u16*)  take((size_t)128*256*2);

  k_prep<<<513, 256, 0, stream>>>(W2, W3, W4, w2t, w3t, w4t,
                                  (const unsigned char*)mask, modep);
  k_stats1<<<2048, 256, 0, stream>>>(x, mask, W1, b1, modep, s1sum, s1sq, cntpart);
  k_red1<<<16, 256, 0, stream>>>(s1sum, s1sq, mid1s, mid1q);
  k_fin1<<<1, 128, 0, stream>>>(mid1s, mid1q, cntpart, W1, b1, g1, be1, w1p, c1p, cntf);
  k_mega<<<RT, 256, 0, stream>>>(x, mask, modep, w1p, c1p, w2t, b2, w3t,
                                 acc3buf, poolpart, s2sum, s2sq);
  k_poolred<<<64, 256, 0, stream>>>(poolpart, W3, b3, s2sum, s2sq, cntpart, P, midS, midQ);
  k_fin2<<<1, 256, 0, stream>>>(midS, midQ, cntf, g2, be2, a2, sh2);
  k_gemm4<<<RT, 256, 0, stream>>>(acc3buf, mask, modep, P, a2, sh2, w4t, b4, outpart);
  k_outred<<<256, 256, 0, stream>>>(outpart, out);
}